// Round 7
// baseline (247.131 us; speedup 1.0000x reference)
//
#include <hip/hip_runtime.h>

#define HW 192
#define DD 512
#define GG 64
#define PP 64
#define SLAB 98304  // 192*512 fp8 bytes per slab

typedef __attribute__((ext_vector_type(4))) int intx4;
typedef __attribute__((ext_vector_type(8))) int intx8;
typedef __attribute__((ext_vector_type(16))) float floatx16;

typedef __attribute__((address_space(3))) unsigned int lds_u32;
typedef const __attribute__((address_space(1))) unsigned int glb_u32;

__device__ __forceinline__ void gload_lds16(const void* g, void* l) {
  __builtin_amdgcn_global_load_lds((glb_u32*)g, (lds_u32*)l, 16, 0, 0);
}

// L2-normalize over channels -> fp8 e4m3, plain K-major ws layout:
// ws[slab][kb2(8)][row(192)][k(64 bytes, contiguous channels kb2*64..+63)].
__global__ __launch_bounds__(512, 2) void norm_kernel(
    const float* __restrict__ gal, const float* __restrict__ prob,
    unsigned char* __restrict__ ws) {
  int b = blockIdx.x;  // 0..1535
  int s = b / 12;      // slab 0..127
  int q = b - s * 12;  // pos chunk 0..11
  const float* in = (s < GG) ? (gal + (size_t)s * DD * HW)
                             : (prob + (size_t)(s - GG) * DD * HW);
  unsigned char* out = ws + (size_t)s * SLAB;
  int pos0 = q * 16;
  int t = threadIdx.x;

  __shared__ float T[16][524];   // 33.5 KB, [pos][c]
  __shared__ float sqa[128][17];
  __shared__ float sq2[16][17];
  __shared__ float scl[16];

  {
    int cq = t >> 2;   // 0..127
    int quad = t & 3;  // 0..3
    float p0 = 0.f, p1 = 0.f, p2 = 0.f, p3 = 0.f;
#pragma unroll
    for (int cb = 0; cb < 4; ++cb) {
      int c = cb * 128 + cq;
      const float4 v = *(const float4*)(in + (size_t)c * HW + pos0 + quad * 4);
      T[quad * 4 + 0][c] = v.x;
      T[quad * 4 + 1][c] = v.y;
      T[quad * 4 + 2][c] = v.z;
      T[quad * 4 + 3][c] = v.w;
      p0 += v.x * v.x; p1 += v.y * v.y; p2 += v.z * v.z; p3 += v.w * v.w;
    }
    sqa[cq][quad * 4 + 0] = p0;
    sqa[cq][quad * 4 + 1] = p1;
    sqa[cq][quad * 4 + 2] = p2;
    sqa[cq][quad * 4 + 3] = p3;
  }
  __syncthreads();
  if (t < 256) {
    int g2 = t >> 4, pos = t & 15;
    float v = 0.f;
#pragma unroll
    for (int r = 0; r < 8; ++r) v += sqa[g2 * 8 + r][pos];
    sq2[g2][pos] = v;
  }
  __syncthreads();
  if (t < 16) {
    float v = 0.f;
#pragma unroll
    for (int r = 0; r < 16; ++r) v += sq2[r][t];
    scl[t] = 1.f / fmaxf(sqrtf(v), 1e-12f);
  }
  __syncthreads();

  {
    int kc = t & 3;          // 16B chunk 0..3
    int pos = (t >> 2) & 15; // 0..15
    int kb2 = t >> 6;        // 0..7
    float sc = scl[pos];
    int base = kb2 * 64 + kc * 16;
    const float4 r0 = *(const float4*)&T[pos][base + 0];
    const float4 r1 = *(const float4*)&T[pos][base + 4];
    const float4 r2 = *(const float4*)&T[pos][base + 8];
    const float4 r3 = *(const float4*)&T[pos][base + 12];
    uint4 u;
    u.x = __builtin_amdgcn_cvt_pk_fp8_f32(r0.x * sc, r0.y * sc, 0, false);
    u.x = __builtin_amdgcn_cvt_pk_fp8_f32(r0.z * sc, r0.w * sc, u.x, true);
    u.y = __builtin_amdgcn_cvt_pk_fp8_f32(r1.x * sc, r1.y * sc, 0, false);
    u.y = __builtin_amdgcn_cvt_pk_fp8_f32(r1.z * sc, r1.w * sc, u.y, true);
    u.z = __builtin_amdgcn_cvt_pk_fp8_f32(r2.x * sc, r2.y * sc, 0, false);
    u.z = __builtin_amdgcn_cvt_pk_fp8_f32(r2.z * sc, r2.w * sc, u.z, true);
    u.w = __builtin_amdgcn_cvt_pk_fp8_f32(r3.x * sc, r3.y * sc, 0, false);
    u.w = __builtin_amdgcn_cvt_pk_fp8_f32(r3.z * sc, r3.w * sc, u.w, true);
    *(uint4*)(out + (size_t)kb2 * 12288 + (size_t)(pos0 + pos) * 64 + kc * 16) = u;
  }
}

// One block per (g,p), fp8 e4m3 via MX-scaled MFMA (unit scales 0x7f = 2^0)
// at 2x non-scaled rate. mfma_scale_f32_32x32x64_f8f6f4: per wave 3x3 tiles
// of 32x32, K=64 per inst => 9 MFMA/kb2 (vs 72 at 16x16x32). Staging and LDS
// traffic identical to r6 (proven 0 conflicts): slot s of row holds global
// chunk s ^ ((row>>1)&3); fragment = two b128 at slot (2h)^key, ^1.
// A layout: row=lane&31, k=(lane>>5)*32+j ; B: col=lane&31 same k.
// C/D (HW-verified m127/m128): col=lane&31, row=(r&3)+8*(r>>2)+4*(lane>>5).
__global__ __launch_bounds__(256, 2) void qaconv_gemm(
    const unsigned char* __restrict__ ws, const float* __restrict__ fcw,
    const float* __restrict__ bnw, const float* __restrict__ bnb,
    const float* __restrict__ bnm, const float* __restrict__ bnv,
    const float* __restrict__ fcb, const float* __restrict__ lw,
    const float* __restrict__ lb, const float* __restrict__ lm,
    const float* __restrict__ lv, float* __restrict__ out) {
  int bid = blockIdx.x;
  int sb = bid >> 6, li = bid & 63;  // 8x8 supertiles for L2 locality
  int g = ((sb >> 3) << 3) + (li >> 3);
  int p = ((sb & 7) << 3) + (li & 7);
  const unsigned char* Bsrc = ws + (size_t)g * SLAB;         // galt[g][j][c]
  const unsigned char* Asrc = ws + (size_t)(GG + p) * SLAB;  // kern[p][i][c]

  __shared__ unsigned char A_lds[2][12288];  // [buf][row(192)][slot(4)][16B]
  __shared__ unsigned char B_lds[2][12288];
  __shared__ float colpart[2][HW];
  __shared__ float rowpart[2][HW];
  __shared__ float redbuf[4][2];

  int tid = threadIdx.x;
  int lane = tid & 63;
  int wave = tid >> 6;
  int wi = wave >> 1, wj = wave & 1;
  int l31 = lane & 31;

  floatx16 acc[3][3];
#pragma unroll
  for (int a = 0; a < 3; ++a)
#pragma unroll
    for (int c = 0; c < 3; ++c) acc[a][c] = (floatx16)(0.f);

  // staging: chunk m -> LDS byte m*16; global = row*64 + (slot^((row>>1)&3))*16
  // (r6-proven: 0 bank conflicts). 4 consecutive lanes = one full 64B line.
  int mIdx[3];
  int mOff[3];
#pragma unroll
  for (int s = 0; s < 3; ++s) {
    int m = tid + s * 256;
    mIdx[s] = m;
    mOff[s] = (m >> 2) * 64 + ((((m & 3) ^ ((m >> 3) & 3))) << 4);
  }

#define STAGE(KB2, BUF)                                             \
  do {                                                              \
    _Pragma("unroll") for (int s_ = 0; s_ < 3; ++s_) {              \
      size_t go = (size_t)(KB2)*12288 + (size_t)mOff[s_];           \
      gload_lds16(Asrc + go, &A_lds[BUF][mIdx[s_] * 16]);           \
      gload_lds16(Bsrc + go, &B_lds[BUF][mIdx[s_] * 16]);           \
    }                                                               \
  } while (0)

  STAGE(0, 0);
  __syncthreads();

  // fragment geometry: key = (row>>1)&3 = (lane>>1)&3 (row offsets are mult of 32)
  int xk = (lane >> 1) & 3;
  int h2 = (lane >> 5) << 1;  // k-half chunk base: 0 or 2
  int slotB0 = (h2 ^ xk) << 4;
  int aO[3], bO[3];
#pragma unroll
  for (int ta = 0; ta < 3; ++ta) aO[ta] = (wi * 96 + ta * 32 + l31) * 64 + slotB0;
#pragma unroll
  for (int tc = 0; tc < 3; ++tc) bO[tc] = (wj * 96 + tc * 32 + l31) * 64 + slotB0;

  const int sc8 = 0x7f7f7f7f;  // four E8M0 scales of 1.0

  for (int kb2 = 0; kb2 < 8; ++kb2) {
    int cur = kb2 & 1;
    if (kb2 < 7) STAGE(kb2 + 1, cur ^ 1);

    intx8 af[3];
#pragma unroll
    for (int ta = 0; ta < 3; ++ta) {
      intx4 lo = *(const intx4*)&A_lds[cur][aO[ta]];
      intx4 hi = *(const intx4*)&A_lds[cur][aO[ta] ^ 16];
      intx8 v;
      v[0] = lo.x; v[1] = lo.y; v[2] = lo.z; v[3] = lo.w;
      v[4] = hi.x; v[5] = hi.y; v[6] = hi.z; v[7] = hi.w;
      af[ta] = v;
    }
#pragma unroll
    for (int tc = 0; tc < 3; ++tc) {
      intx4 lo = *(const intx4*)&B_lds[cur][bO[tc]];
      intx4 hi = *(const intx4*)&B_lds[cur][bO[tc] ^ 16];
      intx8 bf;
      bf[0] = lo.x; bf[1] = lo.y; bf[2] = lo.z; bf[3] = lo.w;
      bf[4] = hi.x; bf[5] = hi.y; bf[6] = hi.z; bf[7] = hi.w;
#pragma unroll
      for (int ta = 0; ta < 3; ++ta)
        acc[ta][tc] = __builtin_amdgcn_mfma_scale_f32_32x32x64_f8f6f4(
            af[ta], bf, acc[ta][tc], 0, 0, 0, sc8, 0, sc8);
    }
    __syncthreads();
  }
#undef STAGE

  // ---- epilogue: dual max-pool ----
  // C/D: i = wi*96 + ta*32 + (r&3)+8*(r>>2)+4*(lane>>5) ; j = wj*96 + tc*32 + (lane&31)
#pragma unroll
  for (int tc = 0; tc < 3; ++tc) {
    float v = -3.4e38f;
#pragma unroll
    for (int ta = 0; ta < 3; ++ta)
#pragma unroll
      for (int r = 0; r < 16; ++r) v = fmaxf(v, acc[ta][tc][r]);
    v = fmaxf(v, __shfl_xor(v, 32, 64));
    if (lane < 32) colpart[wi][wj * 96 + tc * 32 + lane] = v;
  }
#pragma unroll
  for (int ta = 0; ta < 3; ++ta)
#pragma unroll
    for (int r = 0; r < 16; ++r) {
      float v = fmaxf(fmaxf(acc[ta][0][r], acc[ta][1][r]), acc[ta][2][r]);
      v = fmaxf(v, __shfl_xor(v, 1, 64));
      v = fmaxf(v, __shfl_xor(v, 2, 64));
      v = fmaxf(v, __shfl_xor(v, 4, 64));
      v = fmaxf(v, __shfl_xor(v, 8, 64));
      v = fmaxf(v, __shfl_xor(v, 16, 64));
      if (l31 == 0)
        rowpart[wj][wi * 96 + ta * 32 + (r & 3) + 8 * (r >> 2) + ((lane >> 5) << 2)] = v;
    }
  __syncthreads();

  // ---- fused BN -> fc -> lbn -> sigmoid ----
  float part = 0.f, wpart = 0.f;
  if (tid < HW) {
    float cmax = fmaxf(colpart[0][tid], colpart[1][tid]);  // score[j]
    float rmax = fmaxf(rowpart[0][tid], rowpart[1][tid]);  // score[192+i]
    float w1 = fcw[tid], w2 = fcw[HW + tid];
    part = cmax * w1 + rmax * w2;
    wpart = w1 + w2;
  }
#pragma unroll
  for (int off = 32; off > 0; off >>= 1) {
    part += __shfl_down(part, off, 64);
    wpart += __shfl_down(wpart, off, 64);
  }
  if (lane == 0) { redbuf[wave][0] = part; redbuf[wave][1] = wpart; }
  __syncthreads();
  if (tid == 0) {
    float s = redbuf[0][0] + redbuf[1][0] + redbuf[2][0] + redbuf[3][0];
    float wsum = redbuf[0][1] + redbuf[1][1] + redbuf[2][1] + redbuf[3][1];
    float bnA = bnw[0] * rsqrtf(bnv[0] + 1e-5f);
    float bnB = bnb[0] - bnm[0] * bnA;
    float sc = bnA * s + bnB * wsum + fcb[0];
    float lA = lw[0] * rsqrtf(lv[0] + 1e-5f);
    sc = (sc - lm[0]) * lA + lb[0];
    out[g * PP + p] = 1.f / (1.f + __expf(-sc * 0.1f));
  }
}

extern "C" void kernel_launch(void* const* d_in, const int* in_sizes, int n_in,
                              void* d_out, int out_size, void* d_ws, size_t ws_size,
                              hipStream_t stream) {
  const float* gal  = (const float*)d_in[0];
  const float* prob = (const float*)d_in[1];
  const float* bnw  = (const float*)d_in[2];
  const float* bnb  = (const float*)d_in[3];
  const float* bnm  = (const float*)d_in[4];
  const float* bnv  = (const float*)d_in[5];
  const float* fcw  = (const float*)d_in[6];
  const float* fcb  = (const float*)d_in[7];
  const float* lw   = (const float*)d_in[8];
  const float* lb   = (const float*)d_in[9];
  const float* lm   = (const float*)d_in[10];
  const float* lv   = (const float*)d_in[11];
  unsigned char* ws = (unsigned char*)d_ws;
  float* out = (float*)d_out;

  hipLaunchKernelGGL(norm_kernel, dim3(1536), dim3(512), 0, stream, gal, prob, ws);
  hipLaunchKernelGGL(qaconv_gemm, dim3(GG * PP), dim3(256), 0, stream, ws, fcw,
                     bnw, bnb, bnm, bnv, fcb, lw, lb, lm, lv, out);
}

// Round 8
// 216.435 us; speedup vs baseline: 1.1418x; 1.1418x over previous
//
#include <hip/hip_runtime.h>

#define HW 192
#define DD 512
#define GG 64
#define PP 64
#define SLAB 98304  // 192*512 fp8 bytes per slab

typedef __attribute__((ext_vector_type(4))) float floatx4;
typedef __attribute__((ext_vector_type(2))) long long2_t;

// L2-normalize over channels -> fp8 e4m3, MFMA fragment-linear ws layout:
// ws[slab][kb2(8)][R(12)][lane(64)][16B];  R = pos>>4, lane = l4*16 + (pos&15),
// 16B = channels {kb2*64 + l4*8 + 0..7 | kb2*64+32 + l4*8 + 0..7} of that pos.
// This is exactly the per-lane operand order of mfma_f32_16x16x32_fp8_fp8, so
// the GEMM loads fragments straight from global (1KB contiguous per wave-load).
__global__ __launch_bounds__(512, 2) void norm_kernel(
    const float* __restrict__ gal, const float* __restrict__ prob,
    unsigned char* __restrict__ ws) {
  int b = blockIdx.x;  // 0..1535
  int s = b / 12;      // slab 0..127
  int q = b - s * 12;  // pos chunk (= R) 0..11
  const float* in = (s < GG) ? (gal + (size_t)s * DD * HW)
                             : (prob + (size_t)(s - GG) * DD * HW);
  unsigned char* out = ws + (size_t)s * SLAB;
  int pos0 = q * 16;
  int t = threadIdx.x;

  __shared__ float T[16][524];   // 33.5 KB, [pos][c]
  __shared__ float sqa[128][17];
  __shared__ float sq2[16][17];
  __shared__ float scl[16];

  {
    int cq = t >> 2;   // 0..127
    int quad = t & 3;  // 0..3
    float p0 = 0.f, p1 = 0.f, p2 = 0.f, p3 = 0.f;
#pragma unroll
    for (int cb = 0; cb < 4; ++cb) {
      int c = cb * 128 + cq;
      const float4 v = *(const float4*)(in + (size_t)c * HW + pos0 + quad * 4);
      T[quad * 4 + 0][c] = v.x;
      T[quad * 4 + 1][c] = v.y;
      T[quad * 4 + 2][c] = v.z;
      T[quad * 4 + 3][c] = v.w;
      p0 += v.x * v.x; p1 += v.y * v.y; p2 += v.z * v.z; p3 += v.w * v.w;
    }
    sqa[cq][quad * 4 + 0] = p0;
    sqa[cq][quad * 4 + 1] = p1;
    sqa[cq][quad * 4 + 2] = p2;
    sqa[cq][quad * 4 + 3] = p3;
  }
  __syncthreads();
  if (t < 256) {
    int g2 = t >> 4, pos = t & 15;
    float v = 0.f;
#pragma unroll
    for (int r = 0; r < 8; ++r) v += sqa[g2 * 8 + r][pos];
    sq2[g2][pos] = v;
  }
  __syncthreads();
  if (t < 16) {
    float v = 0.f;
#pragma unroll
    for (int r = 0; r < 16; ++r) v += sq2[r][t];
    scl[t] = 1.f / fmaxf(sqrtf(v), 1e-12f);
  }
  __syncthreads();

  {
    int kb2 = t >> 6;        // 0..7
    int lane = t & 63;
    int l4 = lane >> 4;      // k-group 0..3
    int pos = lane & 15;     // 0..15
    float sc = scl[pos];
    int base = kb2 * 64 + l4 * 8;
    const float4 r0 = *(const float4*)&T[pos][base + 0];
    const float4 r1 = *(const float4*)&T[pos][base + 4];
    const float4 r2 = *(const float4*)&T[pos][base + 32];
    const float4 r3 = *(const float4*)&T[pos][base + 36];
    uint4 u;
    u.x = __builtin_amdgcn_cvt_pk_fp8_f32(r0.x * sc, r0.y * sc, 0, false);
    u.x = __builtin_amdgcn_cvt_pk_fp8_f32(r0.z * sc, r0.w * sc, u.x, true);
    u.y = __builtin_amdgcn_cvt_pk_fp8_f32(r1.x * sc, r1.y * sc, 0, false);
    u.y = __builtin_amdgcn_cvt_pk_fp8_f32(r1.z * sc, r1.w * sc, u.y, true);
    u.z = __builtin_amdgcn_cvt_pk_fp8_f32(r2.x * sc, r2.y * sc, 0, false);
    u.z = __builtin_amdgcn_cvt_pk_fp8_f32(r2.z * sc, r2.w * sc, u.z, true);
    u.w = __builtin_amdgcn_cvt_pk_fp8_f32(r3.x * sc, r3.y * sc, 0, false);
    u.w = __builtin_amdgcn_cvt_pk_fp8_f32(r3.z * sc, r3.w * sc, u.w, true);
    *(uint4*)(out + (size_t)kb2 * 12288 + (size_t)q * 1024 + (size_t)lane * 16) = u;
  }
}

// One block per (g,p), fp8 e4m3, 16x16x32 MFMA (r6-proven layout/epilogue).
// NO LDS in the K-loop: fragments load directly global->VGPR from the
// fragment-linear ws (each wave-load = 1KB contiguous), register
// double-buffered (aC/bC vs aN/bN) so kb2+1's 12 loads issue ~1400 cyc ahead.
// No barriers in the loop => no vmcnt(0) drain, waves free-run (m114 overlap).
__global__ __launch_bounds__(256, 2) void qaconv_gemm(
    const unsigned char* __restrict__ ws, const float* __restrict__ fcw,
    const float* __restrict__ bnw, const float* __restrict__ bnb,
    const float* __restrict__ bnm, const float* __restrict__ bnv,
    const float* __restrict__ fcb, const float* __restrict__ lw,
    const float* __restrict__ lb, const float* __restrict__ lm,
    const float* __restrict__ lv, float* __restrict__ out) {
  int bid = blockIdx.x;
  int sb = bid >> 6, li = bid & 63;  // 8x8 supertiles for L2 locality
  int g = ((sb >> 3) << 3) + (li >> 3);
  int p = ((sb & 7) << 3) + (li & 7);
  const unsigned char* Bsrc = ws + (size_t)g * SLAB;         // galt[g] frags
  const unsigned char* Asrc = ws + (size_t)(GG + p) * SLAB;  // kern[p] frags

  __shared__ float colpart[2][HW];
  __shared__ float rowpart[2][HW];
  __shared__ float redbuf[4][2];

  int tid = threadIdx.x;
  int lane = tid & 63;
  int wave = tid >> 6;
  int wi = wave >> 1, wj = wave & 1;
  int l15 = lane & 15, l4 = lane >> 4;

  floatx4 acc[6][6];
#pragma unroll
  for (int a = 0; a < 6; ++a)
#pragma unroll
    for (int c = 0; c < 6; ++c) acc[a][c] = (floatx4){0.f, 0.f, 0.f, 0.f};

  // per-lane fragment base pointers: tile it -> R = wi*6+it (A), wj*6+jt (B)
  const unsigned char* aP = Asrc + (size_t)(wi * 6) * 1024 + (size_t)lane * 16;
  const unsigned char* bP = Bsrc + (size_t)(wj * 6) * 1024 + (size_t)lane * 16;

#define LOADF(AD, BD, KB)                                                 \
  do {                                                                    \
    _Pragma("unroll") for (int it_ = 0; it_ < 6; ++it_) {                 \
      AD[it_] = *(const long2_t*)(aP + (size_t)(KB)*12288 + it_ * 1024);  \
      BD[it_] = *(const long2_t*)(bP + (size_t)(KB)*12288 + it_ * 1024);  \
    }                                                                     \
  } while (0)

#define MFMAB(AD, BD)                                                      \
  do {                                                                     \
    _Pragma("unroll") for (int jt_ = 0; jt_ < 6; ++jt_) {                  \
      long2_t bb = BD[jt_];                                                \
      _Pragma("unroll") for (int it_ = 0; it_ < 6; ++it_)                  \
          acc[it_][jt_] = __builtin_amdgcn_mfma_f32_16x16x32_fp8_fp8(      \
              AD[it_].x, bb.x, acc[it_][jt_], 0, 0, 0);                    \
      _Pragma("unroll") for (int it_ = 0; it_ < 6; ++it_)                  \
          acc[it_][jt_] = __builtin_amdgcn_mfma_f32_16x16x32_fp8_fp8(      \
              AD[it_].y, bb.y, acc[it_][jt_], 0, 0, 0);                    \
    }                                                                      \
  } while (0)

  long2_t aC[6], bC[6], aN[6], bN[6];
  LOADF(aC, bC, 0);
#pragma unroll 1
  for (int kb2 = 0; kb2 < 8; kb2 += 2) {
    LOADF(aN, bN, kb2 + 1);
    MFMAB(aC, bC);
    if (kb2 < 6) LOADF(aC, bC, kb2 + 2);
    MFMAB(aN, bN);
  }
#undef LOADF
#undef MFMAB

  // ---- epilogue: dual max-pool ----
  // C/D layout: i = wi*96 + it*16 + l4*4 + r ; j = wj*96 + jt*16 + l15
  float cm[6];
  float rm[6][4];
#pragma unroll
  for (int jt = 0; jt < 6; ++jt) cm[jt] = -3.4e38f;
#pragma unroll
  for (int it = 0; it < 6; ++it)
#pragma unroll
    for (int r = 0; r < 4; ++r) rm[it][r] = -3.4e38f;
#pragma unroll
  for (int it = 0; it < 6; ++it)
#pragma unroll
    for (int jt = 0; jt < 6; ++jt)
#pragma unroll
      for (int r = 0; r < 4; ++r) {
        float v = acc[it][jt][r];
        cm[jt] = fmaxf(cm[jt], v);
        rm[it][r] = fmaxf(rm[it][r], v);
      }

#pragma unroll
  for (int jt = 0; jt < 6; ++jt) {
    float v = cm[jt];
    v = fmaxf(v, __shfl_xor(v, 16, 64));
    v = fmaxf(v, __shfl_xor(v, 32, 64));
    if (lane < 16) colpart[wi][wj * 96 + jt * 16 + lane] = v;
  }
#pragma unroll
  for (int it = 0; it < 6; ++it)
#pragma unroll
    for (int r = 0; r < 4; ++r) {
      float v = rm[it][r];
      v = fmaxf(v, __shfl_xor(v, 1, 64));
      v = fmaxf(v, __shfl_xor(v, 2, 64));
      v = fmaxf(v, __shfl_xor(v, 4, 64));
      v = fmaxf(v, __shfl_xor(v, 8, 64));
      if (l15 == 0) rowpart[wj][wi * 96 + it * 16 + l4 * 4 + r] = v;
    }
  __syncthreads();

  // ---- fused BN -> fc -> lbn -> sigmoid ----
  float part = 0.f, wpart = 0.f;
  if (tid < HW) {
    float cmax = fmaxf(colpart[0][tid], colpart[1][tid]);  // score[j]
    float rmax = fmaxf(rowpart[0][tid], rowpart[1][tid]);  // score[192+i]
    float w1 = fcw[tid], w2 = fcw[HW + tid];
    part = cmax * w1 + rmax * w2;
    wpart = w1 + w2;
  }
#pragma unroll
  for (int off = 32; off > 0; off >>= 1) {
    part += __shfl_down(part, off, 64);
    wpart += __shfl_down(wpart, off, 64);
  }
  if (lane == 0) { redbuf[wave][0] = part; redbuf[wave][1] = wpart; }
  __syncthreads();
  if (tid == 0) {
    float s = redbuf[0][0] + redbuf[1][0] + redbuf[2][0] + redbuf[3][0];
    float wsum = redbuf[0][1] + redbuf[1][1] + redbuf[2][1] + redbuf[3][1];
    float bnA = bnw[0] * rsqrtf(bnv[0] + 1e-5f);
    float bnB = bnb[0] - bnm[0] * bnA;
    float sc = bnA * s + bnB * wsum + fcb[0];
    float lA = lw[0] * rsqrtf(lv[0] + 1e-5f);
    sc = (sc - lm[0]) * lA + lb[0];
    out[g * PP + p] = 1.f / (1.f + __expf(-sc * 0.1f));
  }
}

extern "C" void kernel_launch(void* const* d_in, const int* in_sizes, int n_in,
                              void* d_out, int out_size, void* d_ws, size_t ws_size,
                              hipStream_t stream) {
  const float* gal  = (const float*)d_in[0];
  const float* prob = (const float*)d_in[1];
  const float* bnw  = (const float*)d_in[2];
  const float* bnb  = (const float*)d_in[3];
  const float* bnm  = (const float*)d_in[4];
  const float* bnv  = (const float*)d_in[5];
  const float* fcw  = (const float*)d_in[6];
  const float* fcb  = (const float*)d_in[7];
  const float* lw   = (const float*)d_in[8];
  const float* lb   = (const float*)d_in[9];
  const float* lm   = (const float*)d_in[10];
  const float* lv   = (const float*)d_in[11];
  unsigned char* ws = (unsigned char*)d_ws;
  float* out = (float*)d_out;

  hipLaunchKernelGGL(norm_kernel, dim3(1536), dim3(512), 0, stream, gal, prob, ws);
  hipLaunchKernelGGL(qaconv_gemm, dim3(GG * PP), dim3(256), 0, stream, ws, fcw,
                     bnw, bnb, bnm, bnv, fcb, lw, lb, lm, lv, out);
}